// Round 14
// baseline (42.879 us; speedup 1.0000x reference)
//
#include <hip/hip_runtime.h>

#pragma clang fp contract(off)

typedef unsigned long long u64;
typedef float f4 __attribute__((ext_vector_type(4)));

#define TOPK 5
#define WAVES 4   // each wave: 1/4 of preds x BOTH gts of the pair

// branchless compare-exchange on u64 keys (ascending)
#define CE(x, y) do { const u64 _a = (x), _b = (y); const bool _l = _b < _a; \
                      (x) = _l ? _b : _a; (y) = _l ? _a : _b; } while (0)

// Markstein-refined division (bit-exact vs reference: absmax 0.0 in R3-R13)
__device__ __forceinline__ float fast_div(float a, float b) {
    float r = __builtin_amdgcn_rcpf(b);
    r = fmaf(fmaf(-b, r, 1.0f), r, r);
    float q = a * r;
    q = fmaf(fmaf(-b, q, a), r, q);
    return q;
}

// one (pred, gt) cost given precomputed pred area
__device__ __forceinline__ u64 eval_one(const f4 pb, const float area_p,
                                        const f4 gb, const float g_area,
                                        const int p) {
    const float cost_bbox = fabsf(pb.x - gb.x) + fabsf(pb.y - gb.y)
                          + fabsf(pb.z - gb.z) + fabsf(pb.w - gb.w);
    const float ltx = fmaxf(pb.x, gb.x), lty = fmaxf(pb.y, gb.y);
    const float rbx = fminf(pb.z, gb.z), rby = fminf(pb.w, gb.w);
    const float iw = fmaxf(rbx - ltx, 0.0f), ih = fmaxf(rby - lty, 0.0f);
    const float inter = iw * ih;
    const float uni = area_p + g_area - inter;
    const float iou = fast_div(inter, uni);
    const float ex1 = fminf(pb.x, gb.x), ey1 = fminf(pb.y, gb.y);
    const float ex2 = fmaxf(pb.z, gb.z), ey2 = fmaxf(pb.w, gb.w);
    const float area_e = (ex2 - ex1) * (ey2 - ey1);
    const float giou = iou - fast_div(area_e - uni, area_e);
    const float cost = cost_bbox + (1.0f - giou);
    return ((u64)__float_as_uint(cost) << 32) | (unsigned)p;
}

__global__ __launch_bounds__(64 * WAVES) void matcher_topk_kernel(
    const float* __restrict__ pred_box,  // [B, NP, 4]
    const float* __restrict__ gt_box,    // [B, NG, 4]
    int* __restrict__ out_pred,          // [B, NG*TOPK]
    int* __restrict__ out_gt,            // [B, NG*TOPK]
    int B, int NP, int NG)
{
    const int pairsPerB = (NG + 1) >> 1;
    const int tp = blockIdx.x;               // one block per (b, gt-pair)
    const int b  = tp / pairsPerB;
    const int j  = tp - b * pairsPerB;
    const int m0 = 2 * j;
    const bool has1 = (m0 + 1 < NG);

    const int wid  = threadIdx.x >> 6;
    const int lane = threadIdx.x & 63;

    const f4 gb0 = ((const f4*)gt_box)[b * NG + m0];
    const f4 gb1 = ((const f4*)gt_box)[b * NG + (has1 ? m0 + 1 : m0)];
    const float ga0 = (gb0.z - gb0.x) * (gb0.w - gb0.y);
    const float ga1 = (gb1.z - gb1.x) * (gb1.w - gb1.y);

    const int NPm1  = NP - 1;
    const int quart = NP >> 2;                // 1250 preds per wave (NP=5000)
    const int wbase = wid * quart;
    // groups of 256 preds (4 loads/lane): 5 for quart=1250 (last masked)
    const int ngroups = (quart + 255) >> 8;

    // two independent top-5 states: a* (gt0), c* (gt1)
    u64 a0 = ~0ULL, a1 = ~0ULL, a2 = ~0ULL, a3 = ~0ULL, a4 = ~0ULL;
    u64 c0 = ~0ULL, c1 = ~0ULL, c2 = ~0ULL, c3 = ~0ULL, c4 = ~0ULL;

    const f4* pbase = (const f4*)pred_box + (size_t)b * NP;

// inline-asm loads: compiler cannot sink/rematerialize (R6/R7/R10 lesson)
#define GLOAD(g, rA, rB, rC, rD) do {                                        \
    const int _i = wbase + ((g) << 8) + lane;                                \
    const f4* _p0 = pbase + min(_i,       NPm1);                             \
    const f4* _p1 = pbase + min(_i + 64,  NPm1);                             \
    const f4* _p2 = pbase + min(_i + 128, NPm1);                             \
    const f4* _p3 = pbase + min(_i + 192, NPm1);                             \
    asm volatile("global_load_dwordx4 %0, %1, off" : "=v"(rA) : "v"(_p0));   \
    asm volatile("global_load_dwordx4 %0, %1, off" : "=v"(rB) : "v"(_p1));   \
    asm volatile("global_load_dwordx4 %0, %1, off" : "=v"(rC) : "v"(_p2));   \
    asm volatile("global_load_dwordx4 %0, %1, off" : "=v"(rD) : "v"(_p3));   \
} while (0)

// retire the oldest in-flight group (steady state 8 -> 4). sched_barrier
// right after: rule #18 (compiler hoists reg-only ops past asm waitcnt).
#define GWAIT() do {                                   \
    asm volatile("s_waitcnt vmcnt(4)");                \
    __builtin_amdgcn_sched_barrier(0);                 \
} while (0)

// sort 4 keys then bitonic lower-5 merge into one state (15 CE equivalent)
#define SORT4_MERGE(kA, kB, kC, kD, s0, s1, s2, s3, s4) do {                 \
    CE(kA, kB); CE(kC, kD); CE(kA, kC); CE(kB, kD); CE(kB, kC);              \
    u64 n0 = s0;                                                             \
    u64 n1 = s1 < kD ? s1 : kD;                                              \
    u64 n2 = s2 < kC ? s2 : kC;                                              \
    u64 n3 = s3 < kB ? s3 : kB;                                              \
    u64 n4 = s4 < kA ? s4 : kA;                                              \
    CE(n0, n1); CE(n3, n4); CE(n2, n4); CE(n2, n3); CE(n1, n4);              \
    CE(n0, n3); CE(n0, n2); CE(n1, n3); CE(n1, n2);                          \
    s0 = n0; s1 = n1; s2 = n2; s3 = n3; s4 = n4;                             \
} while (0)

// 4 preds -> 8 evals (2 gts, shared load+area_p) -> two independent merges
#define PROCG(g, rA, rB, rC, rD) do {                                        \
    const int _li = ((g) << 8) + lane;                                       \
    const int _gi = wbase + _li;                                             \
    const float apA = (rA.z - rA.x) * (rA.w - rA.y);                         \
    const float apB = (rB.z - rB.x) * (rB.w - rB.y);                         \
    const float apC = (rC.z - rC.x) * (rC.w - rC.y);                         \
    const float apD = (rD.z - rD.x) * (rD.w - rD.y);                         \
    u64 kA0 = eval_one(rA, apA, gb0, ga0, _gi);                              \
    u64 kB0 = eval_one(rB, apB, gb0, ga0, _gi + 64);                         \
    u64 kC0 = eval_one(rC, apC, gb0, ga0, _gi + 128);                        \
    u64 kD0 = eval_one(rD, apD, gb0, ga0, _gi + 192);                        \
    u64 kA1 = eval_one(rA, apA, gb1, ga1, _gi);                              \
    u64 kB1 = eval_one(rB, apB, gb1, ga1, _gi + 64);                         \
    u64 kC1 = eval_one(rC, apC, gb1, ga1, _gi + 128);                        \
    u64 kD1 = eval_one(rD, apD, gb1, ga1, _gi + 192);                        \
    if ((g) == ngroups - 1) {   /* compile-time uniform: mask tail */        \
        kA0 = (_li       < quart) ? kA0 : ~0ULL;                             \
        kB0 = (_li + 64  < quart) ? kB0 : ~0ULL;                             \
        kC0 = (_li + 128 < quart) ? kC0 : ~0ULL;                             \
        kD0 = (_li + 192 < quart) ? kD0 : ~0ULL;                             \
        kA1 = (_li       < quart) ? kA1 : ~0ULL;                             \
        kB1 = (_li + 64  < quart) ? kB1 : ~0ULL;                             \
        kC1 = (_li + 128 < quart) ? kC1 : ~0ULL;                             \
        kD1 = (_li + 192 < quart) ? kD1 : ~0ULL;                             \
    }                                                                        \
    SORT4_MERGE(kA0, kB0, kC0, kD0, a0, a1, a2, a3, a4);                     \
    SORT4_MERGE(kA1, kB1, kC1, kD1, c0, c1, c2, c3, c4);                     \
} while (0)

    f4 eA, eB, eC, eD;   // even-phase buffer
    f4 oA, oB, oC, oD;   // odd-phase buffer

    GLOAD(0, eA, eB, eC, eD);
    GLOAD(1, oA, oB, oC, oD);

    for (int g = 0; g < ngroups; g += 2) {
        GWAIT();                                // group g landed
        PROCG(g, eA, eB, eC, eD);
        GLOAD(g + 2, eA, eB, eC, eD);           // clamped; harmless over-issue
        if (g + 1 < ngroups) {                  // uniform
            GWAIT();                            // group g+1 landed
            PROCG(g + 1, oA, oB, oC, oD);
            GLOAD(g + 3, oA, oB, oC, oD);
        }
    }

    // drain in-flight loads; keep dest regs live past the drain (R11 lesson)
    asm volatile("s_waitcnt vmcnt(0)");
    __builtin_amdgcn_sched_barrier(0);
    asm volatile("" :: "v"(eA), "v"(eB), "v"(eC), "v"(eD),
                       "v"(oA), "v"(oB), "v"(oC), "v"(oD));

#undef GLOAD
#undef GWAIT
#undef PROCG

    // wave butterfly: both states per level (independent -> 2x chain ILP)
    #pragma unroll
    for (int off = 1; off < 64; off <<= 1) {
        const u64 sa0 = __shfl_xor(a0, off);
        const u64 sa1 = __shfl_xor(a1, off);
        const u64 sa2 = __shfl_xor(a2, off);
        const u64 sa3 = __shfl_xor(a3, off);
        const u64 sa4 = __shfl_xor(a4, off);
        const u64 sc0 = __shfl_xor(c0, off);
        const u64 sc1 = __shfl_xor(c1, off);
        const u64 sc2 = __shfl_xor(c2, off);
        const u64 sc3 = __shfl_xor(c3, off);
        const u64 sc4 = __shfl_xor(c4, off);

        u64 x0 = a0 < sa4 ? a0 : sa4;
        u64 x1 = a1 < sa3 ? a1 : sa3;
        u64 x2 = a2 < sa2 ? a2 : sa2;
        u64 x3 = a3 < sa1 ? a3 : sa1;
        u64 x4 = a4 < sa0 ? a4 : sa0;
        u64 y0 = c0 < sc4 ? c0 : sc4;
        u64 y1 = c1 < sc3 ? c1 : sc3;
        u64 y2 = c2 < sc2 ? c2 : sc2;
        u64 y3 = c3 < sc1 ? c3 : sc1;
        u64 y4 = c4 < sc0 ? c4 : sc0;
        CE(x0, x1); CE(x3, x4); CE(x2, x4); CE(x2, x3); CE(x1, x4);
        CE(x0, x3); CE(x0, x2); CE(x1, x3); CE(x1, x2);
        CE(y0, y1); CE(y3, y4); CE(y2, y4); CE(y2, y3); CE(y1, y4);
        CE(y0, y3); CE(y0, y2); CE(y1, y3); CE(y1, y2);
        a0 = x0; a1 = x1; a2 = x2; a3 = x3; a4 = x4;
        c0 = y0; c1 = y1; c2 = y2; c3 = y3; c4 = y4;
    }

    // cross-wave merge via LDS: per gt, 4 sorted 5-lists -> final 5
    __shared__ u64 smerge[WAVES][2][TOPK];
    if (lane == 0) {
        smerge[wid][0][0] = a0; smerge[wid][0][1] = a1; smerge[wid][0][2] = a2;
        smerge[wid][0][3] = a3; smerge[wid][0][4] = a4;
        smerge[wid][1][0] = c0; smerge[wid][1][1] = c1; smerge[wid][1][2] = c2;
        smerge[wid][1][3] = c3; smerge[wid][1][4] = c4;
    }
    __syncthreads();

    if (threadIdx.x < 2) {
        const int which = threadIdx.x;       // gt0 / gt1
        if (which == 0 || has1) {
            const int mm = m0 + which;
            int head[WAVES];
            #pragma unroll
            for (int w = 0; w < WAVES; ++w) head[w] = 0;
            const int baseo = (b * NG + mm) * TOPK;
            #pragma unroll
            for (int r = 0; r < TOPK; ++r) {
                u64 best = ~0ULL; int bw = 0;
                #pragma unroll
                for (int w = 0; w < WAVES; ++w) {
                    const u64 v = smerge[w][which][head[w]];
                    if (v < best) { best = v; bw = w; }
                }
                head[bw]++;
                out_pred[baseo + r] = (int)(unsigned)(best & 0xFFFFFFFFu);
                out_gt[baseo + r]   = mm;
            }
        }
    }
}

extern "C" void kernel_launch(void* const* d_in, const int* in_sizes, int n_in,
                              void* d_out, int out_size, void* d_ws, size_t ws_size,
                              hipStream_t stream) {
    const float* pred_box = (const float*)d_in[0];   // [B, NP, 4]
    const float* gt_box   = (const float*)d_in[2];   // [B, NG, 4]

    const int NP = 5000;
    const int B  = in_sizes[1] / NP;                 // pred_obj is [B, NP]
    const int NG = in_sizes[3] / B;                  // gt_obj is [B, NG]

    int* out_pred = (int*)d_out;
    int* out_gt   = out_pred + B * NG * TOPK;

    const int pairsPerB = (NG + 1) >> 1;
    const int blocks = B * pairsPerB;                // one block per gt-pair
    hipLaunchKernelGGL(matcher_topk_kernel, dim3(blocks), dim3(64 * WAVES), 0, stream,
                       pred_box, gt_box, out_pred, out_gt, B, NP, NG);
}

// Round 15
// 40.633 us; speedup vs baseline: 1.0553x; 1.0553x over previous
//
#include <hip/hip_runtime.h>

#pragma clang fp contract(off)

typedef unsigned long long u64;
typedef float f4 __attribute__((ext_vector_type(4)));

#define TOPK 5
#define WAVES 4   // 4 INDEPENDENT waves per block; wave w owns gt (4j+w) fully

// branchless compare-exchange on u64 keys (ascending)
#define CE(x, y) do { const u64 _a = (x), _b = (y); const bool _l = _b < _a; \
                      (x) = _l ? _b : _a; (y) = _l ? _a : _b; } while (0)

// Markstein-refined division (bit-exact vs reference: absmax 0.0 in R3-R14)
__device__ __forceinline__ float fast_div(float a, float b) {
    float r = __builtin_amdgcn_rcpf(b);
    r = fmaf(fmaf(-b, r, 1.0f), r, r);
    float q = a * r;
    q = fmaf(fmaf(-b, q, a), r, q);
    return q;
}

__device__ __forceinline__ u64 eval_key(const f4 pb, const f4 gb,
                                        const float g_area, const int p) {
    const float area_p = (pb.z - pb.x) * (pb.w - pb.y);
    const float cost_bbox = fabsf(pb.x - gb.x) + fabsf(pb.y - gb.y)
                          + fabsf(pb.z - gb.z) + fabsf(pb.w - gb.w);
    const float ltx = fmaxf(pb.x, gb.x), lty = fmaxf(pb.y, gb.y);
    const float rbx = fminf(pb.z, gb.z), rby = fminf(pb.w, gb.w);
    const float iw = fmaxf(rbx - ltx, 0.0f), ih = fmaxf(rby - lty, 0.0f);
    const float inter = iw * ih;
    const float uni = area_p + g_area - inter;
    const float iou = fast_div(inter, uni);
    const float ex1 = fminf(pb.x, gb.x), ey1 = fminf(pb.y, gb.y);
    const float ex2 = fmaxf(pb.z, gb.z), ey2 = fmaxf(pb.w, gb.w);
    const float area_e = (ex2 - ex1) * (ey2 - ey1);
    const float giou = iou - fast_div(area_e - uni, area_e);
    const float cost = cost_bbox + (1.0f - giou);
    return ((u64)__float_as_uint(cost) << 32) | (unsigned)p;
}

__global__ __launch_bounds__(64 * WAVES) void matcher_topk_kernel(
    const float* __restrict__ pred_box,  // [B, NP, 4]
    const float* __restrict__ gt_box,    // [B, NG, 4]
    int* __restrict__ out_pred,          // [B, NG*TOPK]
    int* __restrict__ out_gt,            // [B, NG*TOPK]
    int B, int NP, int NG)
{
    const int quadsPerB = (NG + 3) >> 2;      // 75 for NG=300
    const int tp = blockIdx.x;                // one block per (b, gt-quad)
    const int b  = tp / quadsPerB;
    const int j  = tp - b * quadsPerB;

    const int wid  = threadIdx.x >> 6;
    const int lane = threadIdx.x & 63;
    const int m = 4 * j + wid;                // this wave's gt
    const bool active = (m < NG);
    const int mm = active ? m : NG - 1;       // clamp (inactive wave never writes)

    const f4 gb = ((const f4*)gt_box)[b * NG + mm];
    const float g_area = (gb.z - gb.x) * (gb.w - gb.y);

    const int NPm1    = NP - 1;
    const int ngroups = (NP + 255) >> 8;      // 20 for NP=5000; group = 256 preds

    u64 k0 = ~0ULL, k1 = ~0ULL, k2 = ~0ULL, k3 = ~0ULL, k4 = ~0ULL;

    const f4* pbase = (const f4*)pred_box + (size_t)b * NP;

// inline-asm loads: compiler cannot sink/rematerialize (R6/R7/R10 lesson)
#define GLOAD(g, rA, rB, rC, rD) do {                                        \
    const int _i = ((g) << 8) + lane;                                        \
    const f4* _p0 = pbase + min(_i,       NPm1);                             \
    const f4* _p1 = pbase + min(_i + 64,  NPm1);                             \
    const f4* _p2 = pbase + min(_i + 128, NPm1);                             \
    const f4* _p3 = pbase + min(_i + 192, NPm1);                             \
    asm volatile("global_load_dwordx4 %0, %1, off" : "=v"(rA) : "v"(_p0));   \
    asm volatile("global_load_dwordx4 %0, %1, off" : "=v"(rB) : "v"(_p1));   \
    asm volatile("global_load_dwordx4 %0, %1, off" : "=v"(rC) : "v"(_p2));   \
    asm volatile("global_load_dwordx4 %0, %1, off" : "=v"(rD) : "v"(_p3));   \
} while (0)

// retire the oldest in-flight group (steady state 8 -> 4). sched_barrier
// right after: rule #18 (compiler hoists reg-only ops past asm waitcnt).
#define GWAIT() do {                                   \
    asm volatile("s_waitcnt vmcnt(4)");                \
    __builtin_amdgcn_sched_barrier(0);                 \
} while (0)

// 4 evals (ILP) -> mask tail -> sort4 -> bitonic lower-5 merge into top5
#define PROCG(g, rA, rB, rC, rD) do {                                        \
    const int _i0 = ((g) << 8) + lane;                                       \
    u64 kA = eval_key(rA, gb, g_area, _i0);                                  \
    u64 kB = eval_key(rB, gb, g_area, _i0 + 64);                             \
    u64 kC = eval_key(rC, gb, g_area, _i0 + 128);                            \
    u64 kD = eval_key(rD, gb, g_area, _i0 + 192);                            \
    if ((g) == ngroups - 1) {   /* uniform: mask tail group */               \
        kA = (_i0       < NP) ? kA : ~0ULL;                                  \
        kB = (_i0 + 64  < NP) ? kB : ~0ULL;                                  \
        kC = (_i0 + 128 < NP) ? kC : ~0ULL;                                  \
        kD = (_i0 + 192 < NP) ? kD : ~0ULL;                                  \
    }                                                                        \
    CE(kA, kB); CE(kC, kD); CE(kA, kC); CE(kB, kD); CE(kB, kC);              \
    u64 n0 = k0;                                                             \
    u64 n1 = k1 < kD ? k1 : kD;                                              \
    u64 n2 = k2 < kC ? k2 : kC;                                              \
    u64 n3 = k3 < kB ? k3 : kB;                                              \
    u64 n4 = k4 < kA ? k4 : kA;                                              \
    CE(n0, n1); CE(n3, n4); CE(n2, n4); CE(n2, n3); CE(n1, n4);              \
    CE(n0, n3); CE(n0, n2); CE(n1, n3); CE(n1, n2);                          \
    k0 = n0; k1 = n1; k2 = n2; k3 = n3; k4 = n4;                             \
} while (0)

    f4 eA, eB, eC, eD;   // even-phase buffer
    f4 oA, oB, oC, oD;   // odd-phase buffer

    GLOAD(0, eA, eB, eC, eD);
    GLOAD(1, oA, oB, oC, oD);

    for (int g = 0; g < ngroups; g += 2) {
        GWAIT();                                // group g landed
        PROCG(g, eA, eB, eC, eD);
        GLOAD(g + 2, eA, eB, eC, eD);           // clamped; harmless over-issue
        if (g + 1 < ngroups) {                  // uniform
            GWAIT();                            // group g+1 landed
            PROCG(g + 1, oA, oB, oC, oD);
            GLOAD(g + 3, oA, oB, oC, oD);
        }
    }

    // drain in-flight loads; keep dest regs live past the drain (R11 lesson:
    // allocator recycles them otherwise -> clobber on return)
    asm volatile("s_waitcnt vmcnt(0)");
    __builtin_amdgcn_sched_barrier(0);
    asm volatile("" :: "v"(eA), "v"(eB), "v"(eC), "v"(eD),
                       "v"(oA), "v"(oB), "v"(oC), "v"(oD));

#undef GLOAD
#undef GWAIT
#undef PROCG

    // wave butterfly: merge sorted 5-lists across all 64 lanes -> lane-uniform
    #pragma unroll
    for (int off = 1; off < 64; off <<= 1) {
        const u64 b0 = __shfl_xor(k0, off);
        const u64 b1 = __shfl_xor(k1, off);
        const u64 b2 = __shfl_xor(k2, off);
        const u64 b3 = __shfl_xor(k3, off);
        const u64 b4 = __shfl_xor(k4, off);
        u64 m0_ = k0 < b4 ? k0 : b4;
        u64 m1_ = k1 < b3 ? k1 : b3;
        u64 m2_ = k2 < b2 ? k2 : b2;
        u64 m3_ = k3 < b1 ? k3 : b1;
        u64 m4_ = k4 < b0 ? k4 : b0;
        CE(m0_, m1_); CE(m3_, m4_); CE(m2_, m4_); CE(m2_, m3_); CE(m1_, m4_);
        CE(m0_, m3_); CE(m0_, m2_); CE(m1_, m3_); CE(m1_, m2_);
        k0 = m0_; k1 = m1_; k2 = m2_; k3 = m3_; k4 = m4_;
    }

    // no cross-wave merge needed: this wave owns the gt. lane 0 writes.
    if (active && lane == 0) {
        const int baseo = (b * NG + m) * TOPK;
        out_pred[baseo + 0] = (int)(unsigned)(k0 & 0xFFFFFFFFu);
        out_pred[baseo + 1] = (int)(unsigned)(k1 & 0xFFFFFFFFu);
        out_pred[baseo + 2] = (int)(unsigned)(k2 & 0xFFFFFFFFu);
        out_pred[baseo + 3] = (int)(unsigned)(k3 & 0xFFFFFFFFu);
        out_pred[baseo + 4] = (int)(unsigned)(k4 & 0xFFFFFFFFu);
        out_gt[baseo + 0] = m;
        out_gt[baseo + 1] = m;
        out_gt[baseo + 2] = m;
        out_gt[baseo + 3] = m;
        out_gt[baseo + 4] = m;
    }
}

extern "C" void kernel_launch(void* const* d_in, const int* in_sizes, int n_in,
                              void* d_out, int out_size, void* d_ws, size_t ws_size,
                              hipStream_t stream) {
    const float* pred_box = (const float*)d_in[0];   // [B, NP, 4]
    const float* gt_box   = (const float*)d_in[2];   // [B, NG, 4]

    const int NP = 5000;
    const int B  = in_sizes[1] / NP;                 // pred_obj is [B, NP]
    const int NG = in_sizes[3] / B;                  // gt_obj is [B, NG]

    int* out_pred = (int*)d_out;
    int* out_gt   = out_pred + B * NG * TOPK;

    const int quadsPerB = (NG + 3) >> 2;
    const int blocks = B * quadsPerB;                // 600 for B=8, NG=300
    hipLaunchKernelGGL(matcher_topk_kernel, dim3(blocks), dim3(64 * WAVES), 0, stream,
                       pred_box, gt_box, out_pred, out_gt, B, NP, NG);
}

// Round 16
// 34.891 us; speedup vs baseline: 1.2289x; 1.1646x over previous
//
#include <hip/hip_runtime.h>

#pragma clang fp contract(off)

typedef unsigned long long u64;
typedef float f4 __attribute__((ext_vector_type(4)));

#define TOPK 5
#define WAVES 4   // waves {0,1} -> gt0, waves {2,3} -> gt1 (R12 structure)

// branchless compare-exchange on u64 keys (ascending)
#define CE(x, y) do { const u64 _a = (x), _b = (y); const bool _l = _b < _a; \
                      (x) = _l ? _b : _a; (y) = _l ? _a : _b; } while (0)

// Markstein-refined division (bit-exact vs reference: absmax 0.0 in R3-R15)
__device__ __forceinline__ float fast_div(float a, float b) {
    float r = __builtin_amdgcn_rcpf(b);
    r = fmaf(fmaf(-b, r, 1.0f), r, r);
    float q = a * r;
    q = fmaf(fmaf(-b, q, a), r, q);
    return q;
}

__device__ __forceinline__ u64 eval_key(const f4 pb, const f4 gb,
                                        const float g_area, const int p) {
    const float area_p = (pb.z - pb.x) * (pb.w - pb.y);
    const float cost_bbox = fabsf(pb.x - gb.x) + fabsf(pb.y - gb.y)
                          + fabsf(pb.z - gb.z) + fabsf(pb.w - gb.w);
    const float ltx = fmaxf(pb.x, gb.x), lty = fmaxf(pb.y, gb.y);
    const float rbx = fminf(pb.z, gb.z), rby = fminf(pb.w, gb.w);
    const float iw = fmaxf(rbx - ltx, 0.0f), ih = fmaxf(rby - lty, 0.0f);
    const float inter = iw * ih;
    const float uni = area_p + g_area - inter;
    const float iou = fast_div(inter, uni);
    const float ex1 = fminf(pb.x, gb.x), ey1 = fminf(pb.y, gb.y);
    const float ex2 = fmaxf(pb.z, gb.z), ey2 = fmaxf(pb.w, gb.w);
    const float area_e = (ex2 - ex1) * (ey2 - ey1);
    const float giou = iou - fast_div(area_e - uni, area_e);
    const float cost = cost_bbox + (1.0f - giou);
    return ((u64)__float_as_uint(cost) << 32) | (unsigned)p;
}

__global__ __launch_bounds__(64 * WAVES) void matcher_topk_kernel(
    const float* __restrict__ pred_box,  // [B, NP, 4]
    const float* __restrict__ gt_box,    // [B, NG, 4]
    int* __restrict__ out_pred,          // [B, NG*TOPK]
    int* __restrict__ out_gt,            // [B, NG*TOPK]
    int B, int NP, int NG)
{
    const int pairsPerB = (NG + 1) >> 1;
    const int tp = blockIdx.x;               // one block per (b, gt-pair)
    const int b  = tp / pairsPerB;
    const int j  = tp - b * pairsPerB;
    const int m0 = 2 * j;
    const bool has1 = (m0 + 1 < NG);

    const int wid  = threadIdx.x >> 6;
    const int lane = threadIdx.x & 63;
    const int myGt = wid >> 1;               // 0 or 1
    const int half = wid & 1;                // pred half

    const f4 gb = ((const f4*)gt_box)[b * NG + (myGt ? (has1 ? m0 + 1 : m0) : m0)];
    const float g_area = (gb.z - gb.x) * (gb.w - gb.y);

    const int NPm1  = NP - 1;
    const int hN    = (NP + 1) >> 1;
    const int start = half ? hN : 0;
    const int pend  = half ? NP : hN;
    // 10 groups of 256 preds per wave (2500 preds/half); schedule below is
    // statically unrolled for exactly 10 groups (NP=5000 fixed by harness).

    u64 k0 = ~0ULL, k1 = ~0ULL, k2 = ~0ULL, k3 = ~0ULL, k4 = ~0ULL;

    const f4* pbase = (const f4*)pred_box + (size_t)b * NP;

// FAST load (non-tail groups: whole 256-window in-bounds): ONE address,
// offset-folded immediates -> 3 fewer addr calcs + 6 fewer VGPRs per group.
#define GLOADF(g, rA, rB, rC, rD) do {                                          \
    const f4* _p = pbase + (start + ((g) << 8) + lane);                         \
    asm volatile("global_load_dwordx4 %0, %1, off"             : "=v"(rA) : "v"(_p)); \
    asm volatile("global_load_dwordx4 %0, %1, off offset:1024" : "=v"(rB) : "v"(_p)); \
    asm volatile("global_load_dwordx4 %0, %1, off offset:2048" : "=v"(rC) : "v"(_p)); \
    asm volatile("global_load_dwordx4 %0, %1, off offset:3072" : "=v"(rD) : "v"(_p)); \
} while (0)

// SAFE load (tail group): per-sub clamp (reads dup of last pred; keys masked)
#define GLOADS(g, rA, rB, rC, rD) do {                                          \
    const int _i = start + ((g) << 8) + lane;                                   \
    const f4* _p0 = pbase + min(_i,       NPm1);                                \
    const f4* _p1 = pbase + min(_i + 64,  NPm1);                                \
    const f4* _p2 = pbase + min(_i + 128, NPm1);                                \
    const f4* _p3 = pbase + min(_i + 192, NPm1);                                \
    asm volatile("global_load_dwordx4 %0, %1, off" : "=v"(rA) : "v"(_p0));      \
    asm volatile("global_load_dwordx4 %0, %1, off" : "=v"(rB) : "v"(_p1));      \
    asm volatile("global_load_dwordx4 %0, %1, off" : "=v"(rC) : "v"(_p2));      \
    asm volatile("global_load_dwordx4 %0, %1, off" : "=v"(rD) : "v"(_p3));      \
} while (0)

// counted wait: retire the oldest in-flight group. sched_barrier right after:
// rule #18 (compiler hoists reg-only ops past inline-asm waitcnt otherwise).
#define W(n) do {                                         \
    asm volatile("s_waitcnt vmcnt(" #n ")");              \
    __builtin_amdgcn_sched_barrier(0);                    \
} while (0)

// 4 evals (ILP) -> (tail: mask) -> sort4 -> bitonic lower-5 merge into top5
#define PROCG(g, TAIL, rA, rB, rC, rD) do {                                  \
    const int _i0 = start + ((g) << 8) + lane;                               \
    u64 kA = eval_key(rA, gb, g_area, _i0);                                  \
    u64 kB = eval_key(rB, gb, g_area, _i0 + 64);                             \
    u64 kC = eval_key(rC, gb, g_area, _i0 + 128);                            \
    u64 kD = eval_key(rD, gb, g_area, _i0 + 192);                            \
    if (TAIL) {                                                              \
        kA = (_i0       < pend) ? kA : ~0ULL;                                \
        kB = (_i0 + 64  < pend) ? kB : ~0ULL;                                \
        kC = (_i0 + 128 < pend) ? kC : ~0ULL;                                \
        kD = (_i0 + 192 < pend) ? kD : ~0ULL;                                \
    }                                                                        \
    CE(kA, kB); CE(kC, kD); CE(kA, kC); CE(kB, kD); CE(kB, kC);              \
    u64 n0 = k0;                                                             \
    u64 n1 = k1 < kD ? k1 : kD;                                              \
    u64 n2 = k2 < kC ? k2 : kC;                                              \
    u64 n3 = k3 < kB ? k3 : kB;                                              \
    u64 n4 = k4 < kA ? k4 : kA;                                              \
    CE(n0, n1); CE(n3, n4); CE(n2, n4); CE(n2, n3); CE(n1, n4);              \
    CE(n0, n3); CE(n0, n2); CE(n1, n3); CE(n1, n2);                          \
    k0 = n0; k1 = n1; k2 = n2; k3 = n3; k4 = n4;                             \
} while (0)

    // three buffers -> each group's loads age TWO compute phases before use
    f4 xA, xB, xC, xD;
    f4 yA, yB, yC, yD;
    f4 zA, zB, zC, zD;

    // static 10-group, depth-3 schedule (12 loads in flight steady-state)
    GLOADF(0, xA, xB, xC, xD);
    GLOADF(1, yA, yB, yC, yD);
    GLOADF(2, zA, zB, zC, zD);

    W(8); PROCG(0, false, xA, xB, xC, xD); GLOADF(3, xA, xB, xC, xD);
    W(8); PROCG(1, false, yA, yB, yC, yD); GLOADF(4, yA, yB, yC, yD);
    W(8); PROCG(2, false, zA, zB, zC, zD); GLOADF(5, zA, zB, zC, zD);
    W(8); PROCG(3, false, xA, xB, xC, xD); GLOADF(6, xA, xB, xC, xD);
    W(8); PROCG(4, false, yA, yB, yC, yD); GLOADF(7, yA, yB, yC, yD);
    W(8); PROCG(5, false, zA, zB, zC, zD); GLOADF(8, zA, zB, zC, zD);
    W(8); PROCG(6, false, xA, xB, xC, xD); GLOADS(9, xA, xB, xC, xD);
    W(8); PROCG(7, false, yA, yB, yC, yD);
    W(4); PROCG(8, false, zA, zB, zC, zD);
    W(0); PROCG(9, true,  xA, xB, xC, xD);
    // nothing left in flight after W(0) -> no latent-write hazard (R11 lesson
    // handled structurally: every issued load is consumed before reuse/exit)

#undef GLOADF
#undef GLOADS
#undef W
#undef PROCG

    // wave butterfly: merge sorted 5-lists across all 64 lanes
    #pragma unroll
    for (int off = 1; off < 64; off <<= 1) {
        const u64 b0 = __shfl_xor(k0, off);
        const u64 b1 = __shfl_xor(k1, off);
        const u64 b2 = __shfl_xor(k2, off);
        const u64 b3 = __shfl_xor(k3, off);
        const u64 b4 = __shfl_xor(k4, off);
        u64 m0_ = k0 < b4 ? k0 : b4;
        u64 m1_ = k1 < b3 ? k1 : b3;
        u64 m2_ = k2 < b2 ? k2 : b2;
        u64 m3_ = k3 < b1 ? k3 : b1;
        u64 m4_ = k4 < b0 ? k4 : b0;
        CE(m0_, m1_); CE(m3_, m4_); CE(m2_, m4_); CE(m2_, m3_); CE(m1_, m4_);
        CE(m0_, m3_); CE(m0_, m2_); CE(m1_, m3_); CE(m1_, m2_);
        k0 = m0_; k1 = m1_; k2 = m2_; k3 = m3_; k4 = m4_;
    }

    // cross-wave merge via LDS: per gt, 2 sorted 5-lists -> final 5
    __shared__ u64 lds[WAVES][TOPK];
    if (lane == 0) {
        lds[wid][0] = k0; lds[wid][1] = k1; lds[wid][2] = k2;
        lds[wid][3] = k3; lds[wid][4] = k4;
    }
    __syncthreads();

    if (threadIdx.x < 2) {
        const int which = threadIdx.x;       // gt0 / gt1
        if (which == 0 || has1) {
            const int mm = m0 + which;
            int h0 = 0, h1 = 0;
            const int base = (b * NG + mm) * TOPK;
            #pragma unroll
            for (int r = 0; r < TOPK; ++r) {
                const u64 v0 = lds[which * 2][h0];
                const u64 v1 = lds[which * 2 + 1][h1];
                const bool t = v0 < v1;
                const u64 best = t ? v0 : v1;
                h0 += t; h1 += !t;
                out_pred[base + r] = (int)(unsigned)(best & 0xFFFFFFFFu);
                out_gt[base + r]   = mm;
            }
        }
    }
}

extern "C" void kernel_launch(void* const* d_in, const int* in_sizes, int n_in,
                              void* d_out, int out_size, void* d_ws, size_t ws_size,
                              hipStream_t stream) {
    const float* pred_box = (const float*)d_in[0];   // [B, NP, 4]
    const float* gt_box   = (const float*)d_in[2];   // [B, NG, 4]

    const int NP = 5000;
    const int B  = in_sizes[1] / NP;                 // pred_obj is [B, NP]
    const int NG = in_sizes[3] / B;                  // gt_obj is [B, NG]

    int* out_pred = (int*)d_out;
    int* out_gt   = out_pred + B * NG * TOPK;

    const int pairsPerB = (NG + 1) >> 1;
    const int blocks = B * pairsPerB;                // one block per gt-pair
    hipLaunchKernelGGL(matcher_topk_kernel, dim3(blocks), dim3(64 * WAVES), 0, stream,
                       pred_box, gt_box, out_pred, out_gt, B, NP, NG);
}